// Round 1
// 481.077 us; speedup vs baseline: 1.0890x; 1.0890x over previous
//
#include <hip/hip_runtime.h>
#include <math.h>

#define S     2048
#define D     1024
#define NMEM  32
#define KP    32

__device__ inline float trunc_clip(float v) {
    return truncf(fminf(fmaxf(v, -128.f), 127.f));
}

// ================= K1: entropy (fp64) + column-sum partials, all 33 matrices =================
// grid (NMEM+1)*32 blocks, 256 threads. Block = 64 rows of one matrix (4 waves x 16 rows).
// At the 276 MB memory floor (~44 us) — unchanged from verified version.
__global__ __launch_bounds__(256)
void k_stats(const float* __restrict__ mem, const float* __restrict__ query,
             float* __restrict__ entropy, float* __restrict__ colsumPart) {
    const int tid = threadIdx.x, wave = tid >> 6, lane = tid & 63;
    const int n    = blockIdx.x >> 5;
    const int tile = blockIdx.x & 31;
    const float* src = (n < NMEM) ? (mem + (size_t)n * S * D) : query;
    const int s0 = tile * 64 + wave * 16;

    __shared__ double redsm[64][33];   // [row][lane-pair], padded to kill bank conflicts
    __shared__ double redsq[64][33];
    __shared__ float  ldscol[D];
    for (int i = tid; i < D; i += 256) ldscol[i] = 0.f;
    __syncthreads();

    float colacc[16];
    #pragma unroll
    for (int i = 0; i < 16; ++i) colacc[i] = 0.f;

    for (int r = 0; r < 16; ++r) {
        const float4* row = (const float4*)(src + (size_t)(s0 + r) * D);
        double sm = 0.0, sq = 0.0;
        #pragma unroll
        for (int it = 0; it < 4; ++it) {
            float4 v = row[it * 64 + lane];
            sm += (double)v.x + (double)v.y + (double)v.z + (double)v.w;
            sq += (double)v.x * v.x + (double)v.y * v.y
                + (double)v.z * v.z + (double)v.w * v.w;
            colacc[it*4+0] += v.x; colacc[it*4+1] += v.y;
            colacc[it*4+2] += v.z; colacc[it*4+3] += v.w;
        }
        sm += __shfl_xor(sm, 1, 64);
        sq += __shfl_xor(sq, 1, 64);
        if ((lane & 1) == 0) {
            redsm[wave * 16 + r][lane >> 1] = sm;
            redsq[wave * 16 + r][lane >> 1] = sq;
        }
    }
    #pragma unroll
    for (int it = 0; it < 4; ++it)
        #pragma unroll
        for (int j = 0; j < 4; ++j)
            atomicAdd(&ldscol[it*256 + lane*4 + j], colacc[it*4+j]);
    __syncthreads();

    if (n < NMEM) {
        const int row = tid >> 2, qq = tid & 3;
        double sm = 0.0, sq = 0.0;
        #pragma unroll
        for (int i = 0; i < 8; ++i) { sm += redsm[row][qq*8 + i]; sq += redsq[row][qq*8 + i]; }
        sm += __shfl_xor(sm, 1, 64); sq += __shfl_xor(sq, 1, 64);
        sm += __shfl_xor(sm, 2, 64); sq += __shfl_xor(sq, 2, 64);
        if (qq == 0) {
            double var = (sq - sm * sm / (double)D) / (double)(D - 1);
            entropy[(size_t)n * S + tile * 64 + row] = (float)sqrt(var > 0.0 ? var : 0.0);
        }
    }
    for (int i = tid; i < D; i += 256)
        colsumPart[((size_t)n * 32 + tile) * D + i] = ldscol[i];
}

// ================= K2: parallel rank-count top-32 selection =================
// grid NMEM*8 blocks, 256 threads. Block (n, t8) ranks candidates t8*256..t8*256+255
// of matrix n against all S keys staged in LDS. Same u64 key / strict-greater count
// as the verified 33-block version -> bit-identical selection, 8x the CUs.
__global__ __launch_bounds__(256)
void k_select(const float* __restrict__ entropy, int* __restrict__ idxSel) {
    const int n  = blockIdx.x >> 3;
    const int t8 = blockIdx.x & 7;
    const int tid = threadIdx.x;
    __shared__ unsigned long long key[S];   // 16 KB
    const float* e = entropy + (size_t)n * S;
    for (int i = tid; i < S; i += 256) {
        unsigned int b = __float_as_uint(e[i]);   // e >= 0: bits order-preserving
        key[i] = ((unsigned long long)b << 32) | (unsigned long long)(S - 1 - i);
    }
    __syncthreads();
    const int cand = t8 * 256 + tid;
    const unsigned long long kc = key[cand];
    int c = 0;
    for (int j = 0; j < S; j += 8) {
        unsigned long long a0 = key[j+0], a1 = key[j+1], a2 = key[j+2], a3 = key[j+3];
        unsigned long long a4 = key[j+4], a5 = key[j+5], a6 = key[j+6], a7 = key[j+7];
        c += (a0 > kc) + (a1 > kc) + (a2 > kc) + (a3 > kc)
           + (a4 > kc) + (a5 > kc) + (a6 > kc) + (a7 > kc);
    }
    if (c < KP) idxSel[n * KP + c] = cand;
}

// ================= K3: aggregate rows (gather form) + row entropy of aggregate =================
__global__ __launch_bounds__(256)
void k_aggregate(const float* __restrict__ mem, const float* __restrict__ query,
                 const int* __restrict__ idxSel, float* __restrict__ agg,
                 float* __restrict__ entAgg) {
    const int s = blockIdx.x, tid = threadIdx.x;
    __shared__ int    sidx[NMEM * KP];
    __shared__ int    sel_n[NMEM];
    __shared__ int    selCount;
    __shared__ double rsm[256], rsq[256];
    __shared__ double fsm[64],  fsq[64];
    if (tid == 0) selCount = 0;
    for (int i = tid; i < NMEM * KP; i += 256) sidx[i] = idxSel[i];
    __syncthreads();
    #pragma unroll
    for (int k = 0; k < 4; ++k) {
        int e = tid * 4 + k;
        if (sidx[e] == s) { int p = atomicAdd(&selCount, 1); sel_n[p] = e >> 5; }
    }
    __syncthreads();

    float4 acc = ((const float4*)(query + (size_t)s * D))[tid];
    const int cnt = selCount;
    for (int c = 0; c < cnt; ++c) {
        const int n = sel_n[c];
        float4 v = ((const float4*)(mem + ((size_t)n * S + s) * D))[tid];
        acc.x += trunc_clip(v.x); acc.y += trunc_clip(v.y);
        acc.z += trunc_clip(v.z); acc.w += trunc_clip(v.w);
    }
    const float sc = 1.f / 33.f;
    acc.x *= sc; acc.y *= sc; acc.z *= sc; acc.w *= sc;
    ((float4*)(agg + (size_t)s * D))[tid] = acc;

    double sm = (double)acc.x + (double)acc.y + (double)acc.z + (double)acc.w;
    double sq = (double)acc.x * acc.x + (double)acc.y * acc.y
              + (double)acc.z * acc.z + (double)acc.w * acc.w;
    rsm[tid] = sm; rsq[tid] = sq;
    __syncthreads();
    if (tid < 64) {
        double a = 0, b = 0;
        #pragma unroll
        for (int i = 0; i < 4; ++i) { a += rsm[tid + 64*i]; b += rsq[tid + 64*i]; }
        fsm[tid] = a; fsq[tid] = b;
    }
    __syncthreads();
    if (tid == 0) {
        double a = 0, b = 0;
        for (int i = 0; i < 64; ++i) { a += fsm[i]; b += fsq[i]; }
        double var = (b - a * a / (double)D) / (double)(D - 1);
        entAgg[s] = (float)sqrt(var > 0.0 ? var : 0.0);
    }
}

// ================= K4: reconstruction output with inline rank test =================
__global__ __launch_bounds__(256)
void k_recon(const float* __restrict__ agg, const float* __restrict__ entAgg,
             float* __restrict__ outRecon) {
    const int s = blockIdx.x, tid = threadIdx.x;
    __shared__ float ent[S];
    __shared__ int   cnts[256];
    __shared__ int   rankS;
    for (int i = tid; i < S; i += 256) ent[i] = entAgg[i];
    __syncthreads();
    const float es = ent[s];
    int c = 0;
    for (int i = tid; i < S; i += 256) {
        float ej = ent[i];
        c += (ej > es) || (ej == es && i < s);
    }
    cnts[tid] = c;
    __syncthreads();
    if (tid < 32) {
        int a = 0;
        #pragma unroll
        for (int i = 0; i < 8; ++i) a += cnts[tid + 32 * i];
        cnts[tid] = a;
    }
    __syncthreads();
    if (tid == 0) {
        int r = 0;
        for (int i = 0; i < 32; ++i) r += cnts[i];
        rankS = r;
    }
    __syncthreads();
    float4 o = make_float4(0.f, 0.f, 0.f, 0.f);
    if (rankS < KP) {
        float4 v = ((const float4*)(agg + (size_t)s * D))[tid];
        o.x = trunc_clip(v.x); o.y = trunc_clip(v.y);
        o.z = trunc_clip(v.z); o.w = trunc_clip(v.w);
    }
    ((float4*)(outRecon + (size_t)s * D))[tid] = o;
}

// ================= K5: fused meta-MLP: feats colmean -> L1 -> L2 -> emb + ||emb||^2 =================
// grid NMEM+1 blocks, 256 threads. Identical fp32 accumulation order to the verified
// separate k_mlp1/k_mlp2 kernels; feats kept in LDS (no global round-trip).
__global__ __launch_bounds__(256)
void k_meta(const float* __restrict__ colsumPart, const float* __restrict__ surprise,
            const float* __restrict__ W1, const float* __restrict__ b1,
            const float* __restrict__ W2, const float* __restrict__ b2,
            float* __restrict__ emb, float* __restrict__ ssq) {
    const int m = blockIdx.x, tid = threadIdx.x;
    __shared__ float lf[D];
    __shared__ float lh[128];
    __shared__ float part[256];

    for (int c = tid; c < D; c += 256) {
        float acc = 0.f;
        #pragma unroll 8
        for (int t = 0; t < 32; ++t) acc += colsumPart[((size_t)m * 32 + t) * D + c];
        lf[c] = acc * (1.f / (float)S);
    }
    __syncthreads();

    {   // layer 1: 128 hidden units x 2 j-halves
        const int h = tid & 127, half = tid >> 7;
        const int j0 = half * 512;
        float a0 = 0.f, a1 = 0.f, a2 = 0.f, a3 = 0.f;
        for (int j = 0; j < 512; j += 4) {
            a0 += lf[j0 + j + 0] * W1[(size_t)(j0 + j + 0) * 128 + h];
            a1 += lf[j0 + j + 1] * W1[(size_t)(j0 + j + 1) * 128 + h];
            a2 += lf[j0 + j + 2] * W1[(size_t)(j0 + j + 2) * 128 + h];
            a3 += lf[j0 + j + 3] * W1[(size_t)(j0 + j + 3) * 128 + h];
        }
        part[tid] = (a0 + a1) + (a2 + a3);
        __syncthreads();
        if (half == 0) {
            float acc = b1[h] + part[h] + part[128 + h];
            if (m < NMEM) acc += surprise[m] * W1[(size_t)D * 128 + h];  // j=1024; 1025/1026 zero
            lh[h] = fmaxf(acc, 0.f);
        }
    }
    __syncthreads();

    // layer 2 + squared norm
    const int d0 = tid, d1 = tid + 256, d2 = tid + 512, d3 = tid + 768;
    float a0 = b2[d0], a1 = b2[d1], a2 = b2[d2], a3 = b2[d3];
    for (int k = 0; k < 128; ++k) {
        const float hk = lh[k];
        const float* wr = W2 + (size_t)k * D;
        a0 += hk * wr[d0]; a1 += hk * wr[d1];
        a2 += hk * wr[d2]; a3 += hk * wr[d3];
    }
    float* er = emb + (size_t)m * D;
    er[d0] = a0; er[d1] = a1; er[d2] = a2; er[d3] = a3;

    double ss = (double)a0 * a0 + (double)a1 * a1
              + (double)a2 * a2 + (double)a3 * a3;
    #pragma unroll
    for (int off = 32; off > 0; off >>= 1) ss += __shfl_xor(ss, off, 64);
    __shared__ double wss[4];
    const int wave = tid >> 6, lane = tid & 63;
    if (lane == 0) wss[wave] = ss;
    __syncthreads();
    if (tid == 0) ssq[m] = (float)(wss[0] + wss[1] + wss[2] + wss[3]);
}

// ================= K6: dots + sims + stable descending rank -> top_idx =================
// 1 block, 256 threads = 32 groups of 8; group g computes dot(emb[g], q_emb) in fp64.
__global__ __launch_bounds__(256)
void k_final(const float* __restrict__ emb, const float* __restrict__ ssq,
             const float* __restrict__ prio, float* __restrict__ outSims,
             float* __restrict__ outIdx) {
    const int tid = threadIdx.x;
    __shared__ float qv[D];
    __shared__ float sims[NMEM];
    ((float4*)qv)[tid] = ((const float4*)(emb + (size_t)NMEM * D))[tid];
    __syncthreads();

    const int g = tid >> 3, r = tid & 7;
    const float* er = emb + (size_t)g * D + r * 128;
    const float* qr = qv + r * 128;
    double dt = 0.0;
    #pragma unroll
    for (int k = 0; k < 32; ++k) {
        float4 v = ((const float4*)er)[k];
        float4 q = ((const float4*)qr)[k];
        dt += (double)v.x * q.x + (double)v.y * q.y
            + (double)v.z * q.z + (double)v.w * q.w;
    }
    dt += __shfl_xor(dt, 1, 64);
    dt += __shfl_xor(dt, 2, 64);
    dt += __shfl_xor(dt, 4, 64);
    if (r == 0) {
        const float qn = fmaxf(sqrtf(ssq[NMEM]), 1e-8f);
        const float mn = fmaxf(sqrtf(ssq[g]), 1e-8f);
        const float sv = (float)dt / (mn * qn) * prio[g];
        sims[g] = sv;
        outSims[g] = sv;
    }
    __syncthreads();
    if (tid < NMEM) {
        const float si = sims[tid];
        int rank = 0;
        #pragma unroll
        for (int j = 0; j < NMEM; ++j) {
            const float sj = sims[j];
            rank += (sj > si) || (sj == si && j < tid);
        }
        outIdx[rank] = (float)tid;
    }
}

extern "C" void kernel_launch(void* const* d_in, const int* in_sizes, int n_in,
                              void* d_out, int out_size, void* d_ws, size_t ws_size,
                              hipStream_t stream) {
    const float* query    = (const float*)d_in[0];
    const float* memories = (const float*)d_in[1];
    const float* surprise = (const float*)d_in[2];
    const float* priority = (const float*)d_in[3];
    const float* W1 = (const float*)d_in[4];
    const float* b1 = (const float*)d_in[5];
    const float* W2 = (const float*)d_in[6];
    const float* b2 = (const float*)d_in[7];
    float* out = (float*)d_out;
    char*  ws  = (char*)d_ws;

    // ws layout (bytes)
    float* entropy    = (float*)(ws + 0);          // 262144
    float* colsumPart = (float*)(ws + 262144);     // 4325376
    int*   idxSel     = (int*)  (ws + 4587520);    // 4096
    float* agg        = (float*)(ws + 4591616);    // 8388608
    float* entAgg     = (float*)(ws + 12980224);   // 8192
    float* emb        = (float*)(ws + 12988416);   // 135168
    float* ssq        = (float*)(ws + 13123584);   // 256

    float* outSims   = out + (size_t)S * D;
    float* outTopIdx = outSims + NMEM;

    k_stats    <<<(NMEM + 1) * 32, 256, 0, stream>>>(memories, query, entropy, colsumPart);
    k_select   <<<NMEM * 8,        256, 0, stream>>>(entropy, idxSel);
    k_aggregate<<<S,               256, 0, stream>>>(memories, query, idxSel, agg, entAgg);
    k_recon    <<<S,               256, 0, stream>>>(agg, entAgg, out);
    k_meta     <<<NMEM + 1,        256, 0, stream>>>(colsumPart, surprise, W1, b1, W2, b2, emb, ssq);
    k_final    <<<1,               256, 0, stream>>>(emb, ssq, priority, outSims, outTopIdx);
}

// Round 2
// 459.082 us; speedup vs baseline: 1.1412x; 1.0479x over previous
//
#include <hip/hip_runtime.h>
#include <math.h>

#define S     2048
#define D     1024
#define NMEM  32
#define KP    32

__device__ inline float trunc_clip(float v) {
    return truncf(fminf(fmaxf(v, -128.f), 127.f));
}

// ================= K1: entropy (fp64) + column-sum partials, all 33 matrices =================
// grid (NMEM+1)*32 blocks, 256 threads. Block = 64 rows of one matrix (4 waves x 16 rows).
// At the 276 MB memory floor (~44-55 us) — unchanged from verified version.
__global__ __launch_bounds__(256)
void k_stats(const float* __restrict__ mem, const float* __restrict__ query,
             float* __restrict__ entropy, float* __restrict__ colsumPart) {
    const int tid = threadIdx.x, wave = tid >> 6, lane = tid & 63;
    const int n    = blockIdx.x >> 5;
    const int tile = blockIdx.x & 31;
    const float* src = (n < NMEM) ? (mem + (size_t)n * S * D) : query;
    const int s0 = tile * 64 + wave * 16;

    __shared__ double redsm[64][33];   // [row][lane-pair], padded to kill bank conflicts
    __shared__ double redsq[64][33];
    __shared__ float  ldscol[D];
    for (int i = tid; i < D; i += 256) ldscol[i] = 0.f;
    __syncthreads();

    float colacc[16];
    #pragma unroll
    for (int i = 0; i < 16; ++i) colacc[i] = 0.f;

    for (int r = 0; r < 16; ++r) {
        const float4* row = (const float4*)(src + (size_t)(s0 + r) * D);
        double sm = 0.0, sq = 0.0;
        #pragma unroll
        for (int it = 0; it < 4; ++it) {
            float4 v = row[it * 64 + lane];
            sm += (double)v.x + (double)v.y + (double)v.z + (double)v.w;
            sq += (double)v.x * v.x + (double)v.y * v.y
                + (double)v.z * v.z + (double)v.w * v.w;
            colacc[it*4+0] += v.x; colacc[it*4+1] += v.y;
            colacc[it*4+2] += v.z; colacc[it*4+3] += v.w;
        }
        sm += __shfl_xor(sm, 1, 64);
        sq += __shfl_xor(sq, 1, 64);
        if ((lane & 1) == 0) {
            redsm[wave * 16 + r][lane >> 1] = sm;
            redsq[wave * 16 + r][lane >> 1] = sq;
        }
    }
    #pragma unroll
    for (int it = 0; it < 4; ++it)
        #pragma unroll
        for (int j = 0; j < 4; ++j)
            atomicAdd(&ldscol[it*256 + lane*4 + j], colacc[it*4+j]);
    __syncthreads();

    if (n < NMEM) {
        const int row = tid >> 2, qq = tid & 3;
        double sm = 0.0, sq = 0.0;
        #pragma unroll
        for (int i = 0; i < 8; ++i) { sm += redsm[row][qq*8 + i]; sq += redsq[row][qq*8 + i]; }
        sm += __shfl_xor(sm, 1, 64); sq += __shfl_xor(sq, 1, 64);
        sm += __shfl_xor(sm, 2, 64); sq += __shfl_xor(sq, 2, 64);
        if (qq == 0) {
            double var = (sq - sm * sm / (double)D) / (double)(D - 1);
            entropy[(size_t)n * S + tile * 64 + row] = (float)sqrt(var > 0.0 ? var : 0.0);
        }
    }
    for (int i = tid; i < D; i += 256)
        colsumPart[((size_t)n * 32 + tile) * D + i] = ldscol[i];
}

// ================= K2: fused select (blocks 0..255) + meta-MLP (blocks 256..288) =============
// Both roles depend only on k_stats outputs; fusing hides the ~6us meta chain under select
// and removes one launch gap. Per-role code identical to verified kernels.
__global__ __launch_bounds__(256)
void k_select_meta(const float* __restrict__ entropy, int* __restrict__ idxSel,
                   const float* __restrict__ colsumPart, const float* __restrict__ surprise,
                   const float* __restrict__ W1, const float* __restrict__ b1,
                   const float* __restrict__ W2, const float* __restrict__ b2,
                   float* __restrict__ emb, float* __restrict__ ssq) {
    const int tid = threadIdx.x;
    __shared__ unsigned long long key[S];   // 16 KB (select role)
    __shared__ float lf[D];                 // meta role
    __shared__ float lh[128];
    __shared__ float part[256];

    if (blockIdx.x < NMEM * 8) {
        // ---- select role: rank-count top-32 rows of matrix n ----
        const int n  = blockIdx.x >> 3;
        const int t8 = blockIdx.x & 7;
        const float* e = entropy + (size_t)n * S;
        for (int i = tid; i < S; i += 256) {
            unsigned int b = __float_as_uint(e[i]);   // e >= 0: bits order-preserving
            key[i] = ((unsigned long long)b << 32) | (unsigned long long)(S - 1 - i);
        }
        __syncthreads();
        const int cand = t8 * 256 + tid;
        const unsigned long long kc = key[cand];
        int c = 0;
        for (int j = 0; j < S; j += 8) {
            unsigned long long a0 = key[j+0], a1 = key[j+1], a2 = key[j+2], a3 = key[j+3];
            unsigned long long a4 = key[j+4], a5 = key[j+5], a6 = key[j+6], a7 = key[j+7];
            c += (a0 > kc) + (a1 > kc) + (a2 > kc) + (a3 > kc)
               + (a4 > kc) + (a5 > kc) + (a6 > kc) + (a7 > kc);
        }
        if (c < KP) idxSel[n * KP + c] = cand;
        return;
    }

    // ---- meta role: feats colmean -> L1 -> ReLU -> L2 -> emb + ||emb||^2 ----
    const int m = blockIdx.x - NMEM * 8;
    for (int c = tid; c < D; c += 256) {
        float acc = 0.f;
        #pragma unroll 8
        for (int t = 0; t < 32; ++t) acc += colsumPart[((size_t)m * 32 + t) * D + c];
        lf[c] = acc * (1.f / (float)S);
    }
    __syncthreads();

    {   // layer 1: 128 hidden units x 2 j-halves
        const int h = tid & 127, half = tid >> 7;
        const int j0 = half * 512;
        float a0 = 0.f, a1 = 0.f, a2 = 0.f, a3 = 0.f;
        for (int j = 0; j < 512; j += 4) {
            a0 += lf[j0 + j + 0] * W1[(size_t)(j0 + j + 0) * 128 + h];
            a1 += lf[j0 + j + 1] * W1[(size_t)(j0 + j + 1) * 128 + h];
            a2 += lf[j0 + j + 2] * W1[(size_t)(j0 + j + 2) * 128 + h];
            a3 += lf[j0 + j + 3] * W1[(size_t)(j0 + j + 3) * 128 + h];
        }
        part[tid] = (a0 + a1) + (a2 + a3);
        __syncthreads();
        if (half == 0) {
            float acc = b1[h] + part[h] + part[128 + h];
            if (m < NMEM) acc += surprise[m] * W1[(size_t)D * 128 + h];  // j=1024; 1025/1026 zero
            lh[h] = fmaxf(acc, 0.f);
        }
    }
    __syncthreads();

    // layer 2 + squared norm
    const int d0 = tid, d1 = tid + 256, d2 = tid + 512, d3 = tid + 768;
    float a0 = b2[d0], a1 = b2[d1], a2 = b2[d2], a3 = b2[d3];
    for (int k = 0; k < 128; ++k) {
        const float hk = lh[k];
        const float* wr = W2 + (size_t)k * D;
        a0 += hk * wr[d0]; a1 += hk * wr[d1];
        a2 += hk * wr[d2]; a3 += hk * wr[d3];
    }
    float* er = emb + (size_t)m * D;
    er[d0] = a0; er[d1] = a1; er[d2] = a2; er[d3] = a3;

    double ss = (double)a0 * a0 + (double)a1 * a1
              + (double)a2 * a2 + (double)a3 * a3;
    #pragma unroll
    for (int off = 32; off > 0; off >>= 1) ss += __shfl_xor(ss, off, 64);
    __shared__ double wss[4];
    const int wave = tid >> 6, lane = tid & 63;
    if (lane == 0) wss[wave] = ss;
    __syncthreads();
    if (tid == 0) ssq[m] = (float)(wss[0] + wss[1] + wss[2] + wss[3]);
}

// ================= K3: fused aggregate (blocks 0..2047) + sims/rank final (block 2048) ========
// final depends only on K2's emb/ssq; it rides along with the aggregate dispatch.
__global__ __launch_bounds__(256)
void k_agg_final(const float* __restrict__ mem, const float* __restrict__ query,
                 const int* __restrict__ idxSel, float* __restrict__ agg,
                 float* __restrict__ entAgg,
                 const float* __restrict__ emb, const float* __restrict__ ssq,
                 const float* __restrict__ prio, float* __restrict__ outSims,
                 float* __restrict__ outIdx) {
    const int tid = threadIdx.x;

    if (blockIdx.x < S) {
        // ---- aggregate role: gather selected rows + row entropy of aggregate ----
        const int s = blockIdx.x;
        __shared__ int    sidx[NMEM * KP];
        __shared__ int    sel_n[NMEM];
        __shared__ int    selCount;
        __shared__ double rsm[256], rsq[256];
        __shared__ double fsm[64],  fsq[64];
        if (tid == 0) selCount = 0;
        for (int i = tid; i < NMEM * KP; i += 256) sidx[i] = idxSel[i];
        __syncthreads();
        #pragma unroll
        for (int k = 0; k < 4; ++k) {
            int e = tid * 4 + k;
            if (sidx[e] == s) { int p = atomicAdd(&selCount, 1); sel_n[p] = e >> 5; }
        }
        __syncthreads();

        float4 acc = ((const float4*)(query + (size_t)s * D))[tid];
        const int cnt = selCount;
        for (int c = 0; c < cnt; ++c) {
            const int n = sel_n[c];
            float4 v = ((const float4*)(mem + ((size_t)n * S + s) * D))[tid];
            acc.x += trunc_clip(v.x); acc.y += trunc_clip(v.y);
            acc.z += trunc_clip(v.z); acc.w += trunc_clip(v.w);
        }
        const float sc = 1.f / 33.f;
        acc.x *= sc; acc.y *= sc; acc.z *= sc; acc.w *= sc;
        ((float4*)(agg + (size_t)s * D))[tid] = acc;

        double sm = (double)acc.x + (double)acc.y + (double)acc.z + (double)acc.w;
        double sq = (double)acc.x * acc.x + (double)acc.y * acc.y
                  + (double)acc.z * acc.z + (double)acc.w * acc.w;
        rsm[tid] = sm; rsq[tid] = sq;
        __syncthreads();
        if (tid < 64) {
            double a = 0, b = 0;
            #pragma unroll
            for (int i = 0; i < 4; ++i) { a += rsm[tid + 64*i]; b += rsq[tid + 64*i]; }
            fsm[tid] = a; fsq[tid] = b;
        }
        __syncthreads();
        if (tid == 0) {
            double a = 0, b = 0;
            for (int i = 0; i < 64; ++i) { a += fsm[i]; b += fsq[i]; }
            double var = (b - a * a / (double)D) / (double)(D - 1);
            entAgg[s] = (float)sqrt(var > 0.0 ? var : 0.0);
        }
        return;
    }

    // ---- final role: fp64 dots + sims + stable descending rank -> top_idx ----
    __shared__ float qv[D];
    __shared__ float sims[NMEM];
    ((float4*)qv)[tid] = ((const float4*)(emb + (size_t)NMEM * D))[tid];
    __syncthreads();

    const int g = tid >> 3, r = tid & 7;
    const float* er = emb + (size_t)g * D + r * 128;
    const float* qr = qv + r * 128;
    double dt = 0.0;
    #pragma unroll
    for (int k = 0; k < 32; ++k) {
        float4 v = ((const float4*)er)[k];
        float4 q = ((const float4*)qr)[k];
        dt += (double)v.x * q.x + (double)v.y * q.y
            + (double)v.z * q.z + (double)v.w * q.w;
    }
    dt += __shfl_xor(dt, 1, 64);
    dt += __shfl_xor(dt, 2, 64);
    dt += __shfl_xor(dt, 4, 64);
    if (r == 0) {
        const float qn = fmaxf(sqrtf(ssq[NMEM]), 1e-8f);
        const float mn = fmaxf(sqrtf(ssq[g]), 1e-8f);
        const float sv = (float)dt / (mn * qn) * prio[g];
        sims[g] = sv;
        outSims[g] = sv;
    }
    __syncthreads();
    if (tid < NMEM) {
        const float si = sims[tid];
        int rank = 0;
        #pragma unroll
        for (int j = 0; j < NMEM; ++j) {
            const float sj = sims[j];
            rank += (sj > si) || (sj == si && j < tid);
        }
        outIdx[rank] = (float)tid;
    }
}

// ================= K4: reconstruction output with inline rank test =================
__global__ __launch_bounds__(256)
void k_recon(const float* __restrict__ agg, const float* __restrict__ entAgg,
             float* __restrict__ outRecon) {
    const int s = blockIdx.x, tid = threadIdx.x;
    __shared__ float ent[S];
    __shared__ int   cnts[256];
    __shared__ int   rankS;
    for (int i = tid; i < S; i += 256) ent[i] = entAgg[i];
    __syncthreads();
    const float es = ent[s];
    int c = 0;
    for (int i = tid; i < S; i += 256) {
        float ej = ent[i];
        c += (ej > es) || (ej == es && i < s);
    }
    cnts[tid] = c;
    __syncthreads();
    if (tid < 32) {
        int a = 0;
        #pragma unroll
        for (int i = 0; i < 8; ++i) a += cnts[tid + 32 * i];
        cnts[tid] = a;
    }
    __syncthreads();
    if (tid == 0) {
        int r = 0;
        for (int i = 0; i < 32; ++i) r += cnts[i];
        rankS = r;
    }
    __syncthreads();
    float4 o = make_float4(0.f, 0.f, 0.f, 0.f);
    if (rankS < KP) {
        float4 v = ((const float4*)(agg + (size_t)s * D))[tid];
        o.x = trunc_clip(v.x); o.y = trunc_clip(v.y);
        o.z = trunc_clip(v.z); o.w = trunc_clip(v.w);
    }
    ((float4*)(outRecon + (size_t)s * D))[tid] = o;
}

extern "C" void kernel_launch(void* const* d_in, const int* in_sizes, int n_in,
                              void* d_out, int out_size, void* d_ws, size_t ws_size,
                              hipStream_t stream) {
    const float* query    = (const float*)d_in[0];
    const float* memories = (const float*)d_in[1];
    const float* surprise = (const float*)d_in[2];
    const float* priority = (const float*)d_in[3];
    const float* W1 = (const float*)d_in[4];
    const float* b1 = (const float*)d_in[5];
    const float* W2 = (const float*)d_in[6];
    const float* b2 = (const float*)d_in[7];
    float* out = (float*)d_out;
    char*  ws  = (char*)d_ws;

    // ws layout (bytes)
    float* entropy    = (float*)(ws + 0);          // 262144
    float* colsumPart = (float*)(ws + 262144);     // 4325376
    int*   idxSel     = (int*)  (ws + 4587520);    // 4096
    float* agg        = (float*)(ws + 4591616);    // 8388608
    float* entAgg     = (float*)(ws + 12980224);   // 8192
    float* emb        = (float*)(ws + 12988416);   // 135168
    float* ssq        = (float*)(ws + 13123584);   // 256

    float* outSims   = out + (size_t)S * D;
    float* outTopIdx = outSims + NMEM;

    k_stats      <<<(NMEM + 1) * 32, 256, 0, stream>>>(memories, query, entropy, colsumPart);
    k_select_meta<<<NMEM * 8 + NMEM + 1, 256, 0, stream>>>(entropy, idxSel, colsumPart,
                                                           surprise, W1, b1, W2, b2, emb, ssq);
    k_agg_final  <<<S + 1,           256, 0, stream>>>(memories, query, idxSel, agg, entAgg,
                                                       emb, ssq, priority, outSims, outTopIdx);
    k_recon      <<<S,               256, 0, stream>>>(agg, entAgg, out);
}